// Round 5
// baseline (679.868 us; speedup 1.0000x reference)
//
#include <hip/hip_runtime.h>
#include <math.h>

#define B_    128
#define T_    24
#define NN    300
#define EE    9000
#define GG    (B_ * T_)      // 3072 graphs
#define GRUH  12
#define OUTF  1200
#define GT    16             // graphs per block
#define NGT   (GG / GT)      // 192 g-tiles
#define CC    3              // edge chunks
#define CH    (EE / CC)      // 3000 edges per chunk

// ---------------------------------------------------------------------------
// Kernel 0: pack src|dst<<16 (topology shared by all graphs).
// ---------------------------------------------------------------------------
__global__ __launch_bounds__(256) void pack_edges(
    const int* __restrict__ src, const int* __restrict__ dst,
    unsigned int* __restrict__ pk)
{
    int e = blockIdx.x * 256 + threadIdx.x;
    if (e < EE) pk[e] = (unsigned int)src[e] | ((unsigned int)dst[e] << 16);
}

// ---------------------------------------------------------------------------
// Kernel 1: lane = GRAPH. Block = 16 graphs x 4 waves; wave lane l ->
// (g = l&15, j = l>>4); each step = 4 edges x 16 graphs. src/dst are uniform
// per j-group, so ALL LDS wave-instructions are <=4 segments of 16
// consecutive lanes (<=4/bank, ~1.58x) instead of rounds 1-4's 64-random
// pattern (~100 cyc/instr empirically). ew column access is staged through
// per-wave-PRIVATE 64e x 16g LDS tiles (no barriers in main loop).
// Partials P[c][gt][n][{den,num}][16] identical to round-4 layout.
// ---------------------------------------------------------------------------
__global__ __launch_bounds__(256, 2) void gat_tile(
    const float* __restrict__ x, const float* __restrict__ ew,
    const unsigned int* __restrict__ pk,
    const float* __restrict__ w_node, const float* __restrict__ w_edge,
    const float* __restrict__ attn_l, const float* __restrict__ attn_r,
    const float* __restrict__ attn_e,
    float* __restrict__ P)
{
    __shared__ float xs[NN * 17];        // 20.4 KB  xs[n*17 + g]
    __shared__ float dn[NN * 34];        // 40.8 KB  dn[n*34 + a*17 + g]
    __shared__ float ewt[4 * 64 * 17];   // 17.4 KB  per-wave 64e x 16g tiles

    const int bt  = blockIdx.x;          // g-tile
    const int c   = blockIdx.y;          // edge chunk
    const int tid = threadIdx.x;
    const int g0  = bt * GT;

    // zero den/num
    for (int i = tid; i < NN * 34; i += 256) dn[i] = 0.f;

    // stage x transposed: xs[n*17 + r] = x[(g0+r)*300 + n]
    // write addrs stride 17 (coprime 32) -> conflict-free
    for (int i = tid; i < GT * NN; i += 256) {
        int r = i / NN, n = i - r * NN;
        xs[n * 17 + r] = x[(size_t)(g0 + r) * NN + n];
    }

    float cL = 0.f, cR = 0.f, cE = 0.f;
#pragma unroll
    for (int o = 0; o < 4; o++) {
        float wn = w_node[o];
        cL += wn * attn_l[o];
        cR += wn * attn_r[o];
        cE += w_edge[o] * attn_e[o];
    }
    __syncthreads();

    const int wv   = tid >> 6;
    const int lane = tid & 63;
    const int j    = lane >> 4;          // 0..3 edge sub-lane
    const int g    = lane & 15;          // 0..15 graph lane
    float* mytile  = ewt + wv * 64 * 17;

    const int cbeg = c * CH;
    const int cend = cbeg + CH;
    const int wbeg = cbeg + wv * 768;    // 4 x 768 = 3072 covers 3000 w/ guard

    for (int t0 = 0; t0 < 768; t0 += 64) {
        const int e0 = wbeg + t0;
        if (e0 >= cend) break;           // wave-uniform

        // stage tile: ewt[e_local*17 + r] = ew[(g0+r)*9000 + e0 + e_local]
        // reads: 16x 256B coalesced; writes: stride 17 -> conflict-free
        {
            const int e = e0 + lane;
            const bool ld = (e < cend);
#pragma unroll
            for (int r = 0; r < GT; r++) {
                float v = ld ? ew[(size_t)(g0 + r) * EE + e] : 0.f;
                mytile[lane * 17 + r] = v;
            }
        }
        // wave-private tile: no barrier needed (compiler inserts lgkmcnt)

#pragma unroll 4
        for (int t = 0; t < 16; t++) {
            const int e = e0 + t * 4 + j;
            if (e < cend) {
                unsigned int p = pk[e];          // 4 dwords/wave, L1-hot
                int si = (int)(p & 0xFFFFu);
                int di = (int)(p >> 16);
                float w   = mytile[(t * 4 + j) * 17 + g];
                float xsv = xs[si * 17 + g];
                float xdv = xs[di * 17 + g];
                float v = fmaf(cE, w, fmaf(cL, xsv, cR * xdv));
                v = fmaxf(v, 0.2f * v);          // leaky relu
                float ex = __expf(v);
                unsafeAtomicAdd(&dn[di * 34 + g], ex);
                unsafeAtomicAdd(&dn[di * 34 + 17 + g], ex * xsv);
            }
        }
    }
    __syncthreads();

    // writeout: P[((c*NGT+bt)*300 + n)*32 + a*16 + g], coalesced
    float* Pb = P + (size_t)(c * NGT + bt) * NN * 32;
    for (int i = tid; i < NN * 32; i += 256) {
        int n = i >> 5, r = i & 31, a = r >> 4, gg = r & 15;
        Pb[i] = dn[n * 34 + a * 17 + gg];
    }
}

// ---------------------------------------------------------------------------
// Kernel 2: combine chunk partials -> S[g] = sum_n num_n/den_n.
// ---------------------------------------------------------------------------
__global__ __launch_bounds__(256) void combine_partials(
    const float* __restrict__ P, float* __restrict__ S, int C)
{
    __shared__ float red[256];
    const int tid = threadIdx.x;
    const int g   = blockIdx.x * 64 + (tid & 63);
    const int ns  = tid >> 6;               // 0..3 (n-range split)
    const int gt  = g >> 4, gl = g & 15;

    float acc = 0.f;
    for (int n = ns * 75; n < ns * 75 + 75; n++) {
        float d = 0.f, m = 0.f;
        for (int c = 0; c < C; c++) {
            const float* Pb = P + ((size_t)(c * NGT + gt) * NN + n) * 32;
            d += Pb[gl];
            m += Pb[16 + gl];
        }
        if (d > 0.f) acc += m / d;
    }
    red[tid] = acc;
    __syncthreads();
    if (tid < 64) S[g] = red[tid] + red[tid + 64] + red[tid + 128] + red[tid + 192];
}

// ---------------------------------------------------------------------------
// Fallback (ws too small for partials): round-3 per-graph kernel.
// ---------------------------------------------------------------------------
__global__ __launch_bounds__(256) void gat_pool_fb(
    const float* __restrict__ x, const float* __restrict__ ew,
    const unsigned int* __restrict__ pk,
    const float* __restrict__ w_node, const float* __restrict__ w_edge,
    const float* __restrict__ attn_l, const float* __restrict__ attn_r,
    const float* __restrict__ attn_e,
    float* __restrict__ S)
{
    __shared__ float xs[NN], den[NN], num[NN], red[4];
    const int g = blockIdx.x, tid = threadIdx.x;

    float cL = 0.f, cR = 0.f, cE = 0.f;
#pragma unroll
    for (int o = 0; o < 4; o++) {
        float wn = w_node[o];
        cL += wn * attn_l[o];
        cR += wn * attn_r[o];
        cE += w_edge[o] * attn_e[o];
    }
    const float* xrow = x + (size_t)g * NN;
    const float* erow = ew + (size_t)g * EE;
    for (int i = tid; i < NN; i += 256) { xs[i] = xrow[i]; den[i] = 0.f; num[i] = 0.f; }
    __syncthreads();
    for (int e = tid; e < EE; e += 256) {
        float w = erow[e];
        unsigned int p = pk[e];
        int si = (int)(p & 0xFFFFu), di = (int)(p >> 16);
        float xsv = xs[si];
        float v = fmaf(cE, w, fmaf(cL, xsv, cR * xs[di]));
        v = fmaxf(v, 0.2f * v);
        float ex = __expf(v);
        unsafeAtomicAdd(&den[di], ex);
        unsafeAtomicAdd(&num[di], ex * xsv);
    }
    __syncthreads();
    float acc = 0.f;
    for (int n = tid; n < NN; n += 256) { float d = den[n]; if (d > 0.f) acc += num[n] / d; }
    for (int off = 32; off > 0; off >>= 1) acc += __shfl_down(acc, off);
    if ((tid & 63) == 0) red[tid >> 6] = acc;
    __syncthreads();
    if (tid == 0) S[g] = red[0] + red[1] + red[2] + red[3];
}

// ---------------------------------------------------------------------------
// Kernel 3: GRU (24 steps, hidden 12) on wave 0 + FC (12 -> 1200).
// ---------------------------------------------------------------------------
__device__ __forceinline__ float sigmoidf_(float v) { return 1.0f / (1.0f + __expf(-v)); }

__global__ __launch_bounds__(256) void gru_fc(
    const float* __restrict__ S,
    const float* __restrict__ w_node, const float* __restrict__ gat_bias,
    const float* __restrict__ w_ih, const float* __restrict__ w_hh,
    const float* __restrict__ b_ih, const float* __restrict__ b_hh,
    const float* __restrict__ fc_w, const float* __restrict__ fc_b,
    float* __restrict__ out)
{
    __shared__ float Srow[T_];
    __shared__ float h[GRUH];
    __shared__ float gi_s[36], gh_s[36];

    const int b = blockIdx.x;
    const int tid = threadIdx.x;

    if (tid < T_) Srow[tid] = S[b * T_ + tid];
    if (tid < GRUH) h[tid] = 0.f;
    __syncthreads();

    if (tid < 64) {   // single wave: wave-lockstep LDS, no barriers
        const int lane = tid;
        float wn[4], gb[4];
#pragma unroll
        for (int i = 0; i < 4; i++) {
            wn[i] = w_node[i] * (1.0f / (float)NN);
            gb[i] = gat_bias[i];
        }
        float wih[4], whh[12], bih = 0.f, bhh = 0.f;
        if (lane < 36) {
#pragma unroll
            for (int i = 0; i < 4; i++)  wih[i] = w_ih[lane * 4 + i];
#pragma unroll
            for (int j = 0; j < 12; j++) whh[j] = w_hh[lane * 12 + j];
            bih = b_ih[lane];
            bhh = b_hh[lane];
        }
        for (int t = 0; t < T_; t++) {
            const float Sg = Srow[t];
            if (lane < 36) {
                float gi = bih, gh = bhh;
#pragma unroll
                for (int i = 0; i < 4; i++)  gi += (Sg * wn[i] + gb[i]) * wih[i];
#pragma unroll
                for (int j = 0; j < 12; j++) gh += h[j] * whh[j];
                gi_s[lane] = gi;
                gh_s[lane] = gh;
            }
            if (lane < GRUH) {
                float r = sigmoidf_(gi_s[lane] + gh_s[lane]);
                float z = sigmoidf_(gi_s[12 + lane] + gh_s[12 + lane]);
                float n = tanhf(gi_s[24 + lane] + r * gh_s[24 + lane]);
                h[lane] = (1.f - z) * n + z * h[lane];
            }
        }
    }
    __syncthreads();

    float hr[GRUH];
#pragma unroll
    for (int k = 0; k < GRUH; k++) hr[k] = h[k];

    for (int j = tid; j < OUTF; j += 256) {
        const float4* wr = (const float4*)(fc_w + j * GRUH);
        float4 w0 = wr[0], w1 = wr[1], w2 = wr[2];
        float o = fc_b[j];
        o += hr[0] * w0.x + hr[1] * w0.y + hr[2]  * w0.z + hr[3]  * w0.w;
        o += hr[4] * w1.x + hr[5] * w1.y + hr[6]  * w1.z + hr[7]  * w1.w;
        o += hr[8] * w2.x + hr[9] * w2.y + hr[10] * w2.z + hr[11] * w2.w;
        out[(size_t)b * OUTF + j] = o;
    }
}

// ---------------------------------------------------------------------------
extern "C" void kernel_launch(void* const* d_in, const int* in_sizes, int n_in,
                              void* d_out, int out_size, void* d_ws, size_t ws_size,
                              hipStream_t stream)
{
    const float* x        = (const float*)d_in[0];
    const float* ew       = (const float*)d_in[1];
    const int*   src      = (const int*)d_in[2];
    const int*   dst      = (const int*)d_in[3];
    const float* w_node   = (const float*)d_in[4];
    const float* w_edge   = (const float*)d_in[5];
    const float* attn_l   = (const float*)d_in[6];
    const float* attn_r   = (const float*)d_in[7];
    const float* attn_e   = (const float*)d_in[8];
    const float* gat_bias = (const float*)d_in[9];
    const float* w_ih     = (const float*)d_in[10];
    const float* w_hh     = (const float*)d_in[11];
    const float* b_ih     = (const float*)d_in[12];
    const float* b_hh     = (const float*)d_in[13];
    const float* fc_w     = (const float*)d_in[14];
    const float* fc_b     = (const float*)d_in[15];
    float* out = (float*)d_out;

    // ws layout: S[3072] | pk[9000] | (pad to 64KB) | P[3 * 192*300*32]
    char* ws = (char*)d_ws;
    float*        S  = (float*)ws;                        // 12288 B
    unsigned int* pk = (unsigned int*)(ws + 18432);       // 36000 B
    float*        P  = (float*)(ws + 65536);
    const size_t  pBytes = (size_t)NGT * NN * 32 * sizeof(float);  // 7.37 MB/chunk

    pack_edges<<<(EE + 255) / 256, 256, 0, stream>>>(src, dst, pk);

    if (ws_size >= 65536 + CC * pBytes) {
        gat_tile<<<dim3(NGT, CC), 256, 0, stream>>>(
            x, ew, pk, w_node, w_edge, attn_l, attn_r, attn_e, P);
        combine_partials<<<GG / 64, 256, 0, stream>>>(P, S, CC);
    } else {
        gat_pool_fb<<<GG, 256, 0, stream>>>(
            x, ew, pk, w_node, w_edge, attn_l, attn_r, attn_e, S);
    }

    gru_fc<<<B_, 256, 0, stream>>>(S, w_node, gat_bias, w_ih, w_hh,
                                   b_ih, b_hh, fc_w, fc_b, out);
}

// Round 6
// 445.335 us; speedup vs baseline: 1.5266x; 1.5266x over previous
//
#include <hip/hip_runtime.h>
#include <math.h>

#define B_    128
#define T_    24
#define NN    300
#define EE    9000
#define GG    (B_ * T_)      // 3072 graphs
#define GRUH  12
#define OUTF  1200

// ---------------------------------------------------------------------------
// Kernel 1: EdgeGAT + mean pool for TWO graphs per block (paired per lane).
//   logit = leakyrelu(cL*x[src] + cR*x[dst] + cE*ew)   (scalar collapse, H=1)
//   S[g]  = sum_n num_n/den_n   (no max-shift: |logit|<~15, fp32-safe;
//           validated rounds 1-5, absmax 1.2e-4)
// Design driver (rounds 1-5 post-mortem): wall ~ total wave-instrs/CU at
// ~13-19ns each (downclocked chip); so minimize instructions:
//  - 2 graphs share one ds_read_b64 x-gather, one int4 index load per 8
//    edge-instances, one float4 den/num LDS cell.
//  - no pack/CSR/partials kernels: 2 dispatches total (each costs ~50us).
// ---------------------------------------------------------------------------
__global__ __launch_bounds__(256) void gat2(
    const float* __restrict__ x, const float* __restrict__ ew,
    const int* __restrict__ src, const int* __restrict__ dst,
    const float* __restrict__ w_node, const float* __restrict__ w_edge,
    const float* __restrict__ attn_l, const float* __restrict__ attn_r,
    const float* __restrict__ attn_e,
    float* __restrict__ S)
{
    __shared__ float2 xs2[NN];    // {xA[n], xB[n]}            2.4 KB
    __shared__ float4 dn4[NN];    // {denA, numA, denB, numB}  4.8 KB
    __shared__ float  red[8];

    const int gA  = blockIdx.x * 2;
    const int gB  = gA + 1;
    const int tid = threadIdx.x;

    // scalar attention constants (tiny, L2-broadcast)
    float cL = 0.f, cR = 0.f, cE = 0.f;
#pragma unroll
    for (int o = 0; o < 4; o++) {
        float wn = w_node[o];
        cL += wn * attn_l[o];
        cR += wn * attn_r[o];
        cE += w_edge[o] * attn_e[o];
    }

    const float* xA = x + (size_t)gA * NN;
    const float* xB = x + (size_t)gB * NN;
    for (int i = tid; i < NN; i += 256) {
        xs2[i] = make_float2(xA[i], xB[i]);
        dn4[i] = make_float4(0.f, 0.f, 0.f, 0.f);
    }
    __syncthreads();

    const float4* eA4 = (const float4*)(ew + (size_t)gA * EE);
    const float4* eB4 = (const float4*)(ew + (size_t)gB * EE);
    const int4*   s4  = (const int4*)src;
    const int4*   d4  = (const int4*)dst;

    for (int p = tid; p < EE / 4; p += 256) {
        float4 wA = eA4[p];
        float4 wB = eB4[p];
        int4   s  = s4[p];
        int4   d  = d4[p];
#pragma unroll
        for (int k = 0; k < 4; k++) {
            int   si  = (k == 0) ? s.x : (k == 1) ? s.y : (k == 2) ? s.z : s.w;
            int   di  = (k == 0) ? d.x : (k == 1) ? d.y : (k == 2) ? d.z : d.w;
            float wAv = (k == 0) ? wA.x : (k == 1) ? wA.y : (k == 2) ? wA.z : wA.w;
            float wBv = (k == 0) ? wB.x : (k == 1) ? wB.y : (k == 2) ? wB.z : wB.w;
            float2 xsv = xs2[si];            // one b64 gather serves 2 graphs
            float2 xdv = xs2[di];
            float vA = fmaf(cE, wAv, fmaf(cL, xsv.x, cR * xdv.x));
            float vB = fmaf(cE, wBv, fmaf(cL, xsv.y, cR * xdv.y));
            vA = fmaxf(vA, 0.2f * vA);       // leaky relu
            vB = fmaxf(vB, 0.2f * vB);
            float exA = __expf(vA);
            float exB = __expf(vB);
            float* dnp = (float*)&dn4[di];
            unsafeAtomicAdd(dnp + 0, exA);
            unsafeAtomicAdd(dnp + 1, exA * xsv.x);
            unsafeAtomicAdd(dnp + 2, exB);
            unsafeAtomicAdd(dnp + 3, exB * xsv.y);
        }
    }
    __syncthreads();

    // per-node combine + block reduce (both graphs at once)
    float accA = 0.f, accB = 0.f;
    for (int n = tid; n < NN; n += 256) {
        float4 v = dn4[n];
        if (v.x > 0.f) accA += v.y / v.x;
        if (v.z > 0.f) accB += v.w / v.z;
    }
    for (int off = 32; off > 0; off >>= 1) {
        accA += __shfl_down(accA, off);
        accB += __shfl_down(accB, off);
    }
    if ((tid & 63) == 0) { red[(tid >> 6) * 2] = accA; red[(tid >> 6) * 2 + 1] = accB; }
    __syncthreads();
    if (tid == 0) {
        S[gA] = red[0] + red[2] + red[4] + red[6];
        S[gB] = red[1] + red[3] + red[5] + red[7];
    }
}

// ---------------------------------------------------------------------------
// Kernel 2: GRU (24 steps, hidden 12) on wave 0 + FC (12 -> 1200).
// pooled[b,t,o] = (S[g]/N) * w_node[o] + gat_bias[o]
// ---------------------------------------------------------------------------
__device__ __forceinline__ float sigmoidf_(float v) { return 1.0f / (1.0f + __expf(-v)); }

__global__ __launch_bounds__(256) void gru_fc(
    const float* __restrict__ S,
    const float* __restrict__ w_node, const float* __restrict__ gat_bias,
    const float* __restrict__ w_ih, const float* __restrict__ w_hh,
    const float* __restrict__ b_ih, const float* __restrict__ b_hh,
    const float* __restrict__ fc_w, const float* __restrict__ fc_b,
    float* __restrict__ out)
{
    __shared__ float Srow[T_];
    __shared__ float h[GRUH];
    __shared__ float gi_s[36], gh_s[36];

    const int b = blockIdx.x;
    const int tid = threadIdx.x;

    if (tid < T_) Srow[tid] = S[b * T_ + tid];
    if (tid < GRUH) h[tid] = 0.f;
    __syncthreads();

    if (tid < 64) {   // single wave: wave-lockstep LDS, no barriers
        const int lane = tid;
        float wn[4], gb[4];
#pragma unroll
        for (int i = 0; i < 4; i++) {
            wn[i] = w_node[i] * (1.0f / (float)NN);
            gb[i] = gat_bias[i];
        }
        float wih[4], whh[12], bih = 0.f, bhh = 0.f;
        if (lane < 36) {
#pragma unroll
            for (int i = 0; i < 4; i++)  wih[i] = w_ih[lane * 4 + i];
#pragma unroll
            for (int j = 0; j < 12; j++) whh[j] = w_hh[lane * 12 + j];
            bih = b_ih[lane];
            bhh = b_hh[lane];
        }
        for (int t = 0; t < T_; t++) {
            const float Sg = Srow[t];
            if (lane < 36) {
                float gi = bih, gh = bhh;
#pragma unroll
                for (int i = 0; i < 4; i++)  gi += (Sg * wn[i] + gb[i]) * wih[i];
#pragma unroll
                for (int j = 0; j < 12; j++) gh += h[j] * whh[j];
                gi_s[lane] = gi;
                gh_s[lane] = gh;
            }
            if (lane < GRUH) {
                float r = sigmoidf_(gi_s[lane] + gh_s[lane]);
                float z = sigmoidf_(gi_s[12 + lane] + gh_s[12 + lane]);
                float n = tanhf(gi_s[24 + lane] + r * gh_s[24 + lane]);
                h[lane] = (1.f - z) * n + z * h[lane];
            }
        }
    }
    __syncthreads();

    float hr[GRUH];
#pragma unroll
    for (int k = 0; k < GRUH; k++) hr[k] = h[k];

    for (int j = tid; j < OUTF; j += 256) {
        const float4* wr = (const float4*)(fc_w + j * GRUH);
        float4 w0 = wr[0], w1 = wr[1], w2 = wr[2];
        float o = fc_b[j];
        o += hr[0] * w0.x + hr[1] * w0.y + hr[2]  * w0.z + hr[3]  * w0.w;
        o += hr[4] * w1.x + hr[5] * w1.y + hr[6]  * w1.z + hr[7]  * w1.w;
        o += hr[8] * w2.x + hr[9] * w2.y + hr[10] * w2.z + hr[11] * w2.w;
        out[(size_t)b * OUTF + j] = o;
    }
}

// ---------------------------------------------------------------------------
extern "C" void kernel_launch(void* const* d_in, const int* in_sizes, int n_in,
                              void* d_out, int out_size, void* d_ws, size_t ws_size,
                              hipStream_t stream)
{
    const float* x        = (const float*)d_in[0];
    const float* ew       = (const float*)d_in[1];
    const int*   src      = (const int*)d_in[2];
    const int*   dst      = (const int*)d_in[3];
    const float* w_node   = (const float*)d_in[4];
    const float* w_edge   = (const float*)d_in[5];
    const float* attn_l   = (const float*)d_in[6];
    const float* attn_r   = (const float*)d_in[7];
    const float* attn_e   = (const float*)d_in[8];
    const float* gat_bias = (const float*)d_in[9];
    const float* w_ih     = (const float*)d_in[10];
    const float* w_hh     = (const float*)d_in[11];
    const float* b_ih     = (const float*)d_in[12];
    const float* b_hh     = (const float*)d_in[13];
    const float* fc_w     = (const float*)d_in[14];
    const float* fc_b     = (const float*)d_in[15];
    float* out = (float*)d_out;

    float* S = (float*)d_ws;   // GG floats

    gat2<<<GG / 2, 256, 0, stream>>>(x, ew, src, dst, w_node, w_edge,
                                     attn_l, attn_r, attn_e, S);
    gru_fc<<<B_, 256, 0, stream>>>(S, w_node, gat_bias, w_ih, w_hh,
                                   b_ih, b_hh, fc_w, fc_b, out);
}